// Round 3
// baseline (354.868 us; speedup 1.0000x reference)
//
#include <hip/hip_runtime.h>
#include <stdint.h>

typedef __attribute__((ext_vector_type(8))) short short8;
typedef __attribute__((ext_vector_type(8))) unsigned short ushort8;
typedef __attribute__((ext_vector_type(4))) float f32x4;

#define NNODES 4096
#define NEDGES 262144
#define DIM 128
#define NENT 50000
#define NENTP 50048  // padded to 782*64
#define NTILES 782   // ceil(50000/64)
#define NSPLIT 16
#define CHUNK 49     // ceil(782/16)

__device__ __forceinline__ unsigned short f2bf(float f) {
  union { float f; unsigned u; } c; c.f = f;
  unsigned r = (c.u + 0x7FFFu + ((c.u >> 16) & 1u)) >> 16;
  return (unsigned short)r;
}

// ---------------- kernel 1: edge scatter via int atomics (fixed-point 2^16) ----
__global__ __launch_bounds__(256) void k_scatter(
    const int* __restrict__ ei, const int* __restrict__ rid,
    const int* __restrict__ nf, const float* __restrict__ x,
    const float* __restrict__ rel, int* __restrict__ aggr_i)
{
  const int t = threadIdx.x;
  const int d = t & 127;
  const int half = t >> 7;
  const int e0 = blockIdx.x * 16;
#pragma unroll
  for (int i = 0; i < 8; ++i) {
    int e = e0 + i * 2 + half;
    int src = ei[e];
    int dst = ei[NEDGES + e];
    int r = rid[e];
    float coef = 1.f - 2.f * (float)nf[e];
    float v = (x[src * DIM + d] + rel[r * DIM + d]) * coef;
    atomicAdd(&aggr_i[dst * DIM + d], (int)rintf(v * 65536.f));
  }
}

// ---------------- kernel 2: q = bf16(0.1*x + aggr) ----------------
__global__ __launch_bounds__(256) void k_buildq(
    const float* __restrict__ x, const int* __restrict__ aggr_i,
    unsigned short* __restrict__ q)
{
  int i = blockIdx.x * 256 + threadIdx.x;
  q[i] = f2bf(0.1f * x[i] + (float)aggr_i[i] * (1.f / 65536.f));
}

// ---------------- kernel 3: one-shot E f32 -> bf16 row-major + transposed ----
__global__ __launch_bounds__(256) void k_prep(
    const float* __restrict__ ent, unsigned short* __restrict__ ebf,
    unsigned short* __restrict__ etbf)
{
  __shared__ float sT[64 * 133];  // pad 133: stride-133 column reads -> ~2-way (free)
  const int t = threadIdx.x;
  const int e0 = blockIdx.x * 64;
#pragma unroll
  for (int i = 0; i < 8; ++i) {
    int idx = i * 256 + t;        // 0..2047
    int e = idx >> 5;             // 0..63
    int c4 = idx & 31;            // float4 chunk
    float4 v = make_float4(0.f, 0.f, 0.f, 0.f);
    if (e0 + e < NENT) v = reinterpret_cast<const float4*>(ent)[(e0 + e) * 32 + c4];
    *reinterpret_cast<float4*>(&sT[e * 133 + c4 * 4]) = v;
    ushort4 b;
    b.x = f2bf(v.x); b.y = f2bf(v.y); b.z = f2bf(v.z); b.w = f2bf(v.w);
    *reinterpret_cast<ushort4*>(&ebf[(e0 + e) * 128 + c4 * 4]) = b;
  }
  __syncthreads();
  const int lane = t & 63;
  const int w = t >> 6;           // 4 waves
  const int dl = lane >> 3;       // 0..7
  const int el = (lane & 7) * 8;  // 0..56
#pragma unroll
  for (int it = 0; it < 4; ++it) {
    int d = it * 32 + w * 8 + dl; // 0..127
    ushort8 buf;
#pragma unroll
    for (int j = 0; j < 8; ++j) buf[j] = f2bf(sT[(el + j) * 133 + d]);
    *reinterpret_cast<ushort8*>(&etbf[d * NENTP + e0 + el]) = buf;
  }
}

// ---------------- kernel 4: fused relu-"attention" over entity table ----------------
__global__ __launch_bounds__(512, 4) void k_flash(
    const unsigned short* __restrict__ qg,     // [4096][128] bf16
    const unsigned short* __restrict__ ebf,    // [50048][128] bf16
    const unsigned short* __restrict__ etbf,   // [128][50048] bf16
    const float* __restrict__ scale,           // [50000] f32
    const float* __restrict__ bias,            // [50000] f32
    float* __restrict__ out)                   // [4096][128] f32 accum
{
  __shared__ __align__(16) unsigned short sE[64 * 136];   // E-tile row-major
  __shared__ __align__(16) unsigned short sET[128 * 72];  // E-tile transposed; Q staging
  __shared__ __align__(16) unsigned short sP[128 * 72];   // P tile
  __shared__ float sScale[64];
  __shared__ float sBias[64];

  const int t = threadIdx.x;
  const int lane = t & 63;
  const int w = t >> 6;       // wave 0..7
  const int wm = w >> 1;      // 0..3 : 32-row strip
  const int wn = w & 1;       // 0..1
  const int l15 = lane & 15;
  const int quad = lane >> 4; // 0..3

  const int m0 = blockIdx.x * 128;
  const int tile_lo = blockIdx.y * CHUNK;
  const int tile_hi = (tile_lo + CHUNK < NTILES) ? (tile_lo + CHUNK) : NTILES;

  // ---- stage Q through sET in two 64-row halves; preload A-frags to regs ----
  short8 qf[2][4];
  for (int h = 0; h < 2; ++h) {
#pragma unroll
    for (int i = 0; i < 2; ++i) {
      int idx = i * 512 + t;       // 0..1023
      int v = idx >> 4;            // row 0..63
      int ch = idx & 15;           // 16B chunk
      uint4 val = reinterpret_cast<const uint4*>(qg)[(m0 + h * 64 + v) * 16 + ch];
      *reinterpret_cast<uint4*>(&sET[v * 136 + ch * 8]) = val;
    }
    __syncthreads();
    if ((wm >> 1) == h) {
      int lr = (wm & 1) * 32;
#pragma unroll
      for (int tm = 0; tm < 2; ++tm)
#pragma unroll
        for (int kk = 0; kk < 4; ++kk)
          qf[tm][kk] = *reinterpret_cast<const short8*>(
              &sET[(lr + tm * 16 + l15) * 136 + kk * 32 + quad * 8]);
    }
    __syncthreads();
  }

  f32x4 accO[2][4];
#pragma unroll
  for (int tm = 0; tm < 2; ++tm)
#pragma unroll
    for (int td = 0; td < 4; ++td) accO[tm][td] = {0.f, 0.f, 0.f, 0.f};

  for (int tile = tile_lo; tile < tile_hi; ++tile) {
    const int vt0 = tile * 64;

    if (t < 64) {
      int e = vt0 + t;
      sScale[t] = (e < NENT) ? scale[e] : 0.f;
      sBias[t]  = (e < NENT) ? bias[e]  : 0.f;
    }
    // sE: 64 rows x 128 bf16 (row-major copy)
#pragma unroll
    for (int i = 0; i < 2; ++i) {
      int idx = i * 512 + t;
      int v = idx >> 4, ch = idx & 15;
      ushort8 val = *reinterpret_cast<const ushort8*>(&ebf[(vt0 + v) * 128 + ch * 8]);
      *reinterpret_cast<ushort8*>(&sE[v * 136 + ch * 8]) = val;
    }
    // sET: 128 rows x 64 bf16 (copy from precomputed transpose)
#pragma unroll
    for (int i = 0; i < 2; ++i) {
      int idx = i * 512 + t;
      int d = idx >> 3, ch = idx & 7;
      ushort8 val = *reinterpret_cast<const ushort8*>(&etbf[d * NENTP + vt0 + ch * 8]);
      *reinterpret_cast<ushort8*>(&sET[d * 72 + ch * 8]) = val;
    }
    __syncthreads();

    // ---- S = Q @ E^T : wave computes S[32][32] ----
    f32x4 accS[2][2];
#pragma unroll
    for (int tm = 0; tm < 2; ++tm)
#pragma unroll
      for (int tn = 0; tn < 2; ++tn) accS[tm][tn] = {0.f, 0.f, 0.f, 0.f};
#pragma unroll
    for (int kk = 0; kk < 4; ++kk) {
      short8 bE[2];
#pragma unroll
      for (int tn = 0; tn < 2; ++tn)
        bE[tn] = *reinterpret_cast<const short8*>(
            &sE[(wn * 32 + tn * 16 + l15) * 136 + kk * 32 + quad * 8]);
#pragma unroll
      for (int tm = 0; tm < 2; ++tm)
#pragma unroll
        for (int tn = 0; tn < 2; ++tn)
          accS[tm][tn] = __builtin_amdgcn_mfma_f32_16x16x32_bf16(
              qf[tm][kk], bE[tn], accS[tm][tn], 0, 0, 0);
    }

    // ---- epilogue: P = bf16(relu(S*scale + bias)) ----
#pragma unroll
    for (int tm = 0; tm < 2; ++tm)
#pragma unroll
      for (int tn = 0; tn < 2; ++tn) {
        int col = wn * 32 + tn * 16 + l15;
        float sc = sScale[col], bs = sBias[col];
#pragma unroll
        for (int r = 0; r < 4; ++r) {
          int row = wm * 32 + tm * 16 + quad * 4 + r;
          sP[row * 72 + col] = f2bf(fmaxf(accS[tm][tn][r] * sc + bs, 0.f));
        }
      }
    __syncthreads();

    // ---- O += P @ E : wave computes O[32][64] ----
#pragma unroll
    for (int kk = 0; kk < 2; ++kk) {
      short8 aP[2], bT[4];
#pragma unroll
      for (int tm = 0; tm < 2; ++tm)
        aP[tm] = *reinterpret_cast<const short8*>(
            &sP[(wm * 32 + tm * 16 + l15) * 72 + kk * 32 + quad * 8]);
#pragma unroll
      for (int td = 0; td < 4; ++td)
        bT[td] = *reinterpret_cast<const short8*>(
            &sET[(wn * 64 + td * 16 + l15) * 72 + kk * 32 + quad * 8]);
#pragma unroll
      for (int tm = 0; tm < 2; ++tm)
#pragma unroll
        for (int td = 0; td < 4; ++td)
          accO[tm][td] = __builtin_amdgcn_mfma_f32_16x16x32_bf16(
              aP[tm], bT[td], accO[tm][td], 0, 0, 0);
    }
    __syncthreads();
  }

  // ---- accumulate partial O into f32 output ----
#pragma unroll
  for (int tm = 0; tm < 2; ++tm)
#pragma unroll
    for (int td = 0; td < 4; ++td)
#pragma unroll
      for (int r = 0; r < 4; ++r) {
        int row = m0 + wm * 32 + tm * 16 + quad * 4 + r;
        int col = wn * 64 + td * 16 + l15;
        atomicAdd(&out[row * DIM + col], accO[tm][td][r]);
      }
}

extern "C" void kernel_launch(void* const* d_in, const int* in_sizes, int n_in,
                              void* d_out, int out_size, void* d_ws, size_t ws_size,
                              hipStream_t stream) {
  const float* x     = (const float*)d_in[0];
  const int*   ei    = (const int*)d_in[1];
  const int*   rid   = (const int*)d_in[2];
  const int*   nf    = (const int*)d_in[3];
  const float* rel   = (const float*)d_in[4];
  const float* ent   = (const float*)d_in[5];
  const float* scale = (const float*)d_in[6];
  const float* bias  = (const float*)d_in[7];
  float* out = (float*)d_out;

  // workspace layout (all 16B aligned): ~28.6 MB total
  int*            aggr_i = (int*)d_ws;                                  // 2 MB
  unsigned short* qb     = (unsigned short*)((char*)d_ws + (2u << 20)); // 1 MB
  unsigned short* ebf    = (unsigned short*)((char*)d_ws + (3u << 20)); // 12.8 MB
  unsigned short* etbf   = (unsigned short*)((char*)d_ws + (3u << 20) + (size_t)NENTP * DIM * 2);

  hipMemsetAsync(aggr_i, 0, (size_t)NNODES * DIM * sizeof(int), stream);
  hipMemsetAsync(d_out, 0, (size_t)out_size * sizeof(float), stream);
  k_prep<<<NTILES, 256, 0, stream>>>(ent, ebf, etbf);
  k_scatter<<<NEDGES / 16, 256, 0, stream>>>(ei, rid, nf, x, rel, aggr_i);
  k_buildq<<<NNODES * DIM / 256, 256, 0, stream>>>(x, aggr_i, qb);
  k_flash<<<dim3(NNODES / 128, NSPLIT), 512, 0, stream>>>(qb, ebf, etbf, scale, bias, out);
}

// Round 4
// 300.526 us; speedup vs baseline: 1.1808x; 1.1808x over previous
//
#include <hip/hip_runtime.h>
#include <stdint.h>

typedef __attribute__((ext_vector_type(8))) short short8;
typedef __attribute__((ext_vector_type(8))) unsigned short ushort8;
typedef __attribute__((ext_vector_type(4))) float f32x4;

#define NNODES 4096
#define NEDGES 262144
#define DIM 128
#define NENT 50000
#define NENTP 50048  // padded to 782*64
#define NTILES 782   // ceil(50000/64)
#define NSPLIT 16
#define CHUNK 49     // ceil(782/16)

__device__ __forceinline__ unsigned short f2bf(float f) {
  union { __bf16 b; unsigned short u; } c;
  c.b = (__bf16)f;   // RNE; gfx950 has HW bf16 cvt
  return c.u;
}

// ---------------- scatter pipeline: hist -> scan -> place -> aggregate ----------------
__global__ __launch_bounds__(256) void k_hist(
    const int* __restrict__ ei, int* __restrict__ cnt)
{
  int e = blockIdx.x * 256 + threadIdx.x;
  atomicAdd(&cnt[ei[NEDGES + e]], 1);
}

__global__ __launch_bounds__(1024) void k_scan(
    const int* __restrict__ cnt, int* __restrict__ off, int* __restrict__ cur)
{
  __shared__ int s[1024];
  int t = threadIdx.x;
  int4 v = reinterpret_cast<const int4*>(cnt)[t];
  int lsum = v.x + v.y + v.z + v.w;
  s[t] = lsum; __syncthreads();
  for (int d = 1; d < 1024; d <<= 1) {
    int a = (t >= d) ? s[t - d] : 0;
    __syncthreads();
    s[t] += a;
    __syncthreads();
  }
  int base = s[t] - lsum;  // exclusive prefix
  int4 o; o.x = base; o.y = base + v.x; o.z = o.y + v.y; o.w = o.z + v.z;
  reinterpret_cast<int4*>(off)[t] = o;
  reinterpret_cast<int4*>(cur)[t] = o;
  if (t == 1023) off[4096] = base + lsum;
}

__global__ __launch_bounds__(256) void k_place(
    const int* __restrict__ ei, const int* __restrict__ rid,
    const int* __restrict__ nf, int* __restrict__ cur, int* __restrict__ sorted)
{
  int e = blockIdx.x * 256 + threadIdx.x;
  int dst = ei[NEDGES + e];
  int pos = atomicAdd(&cur[dst], 1);
  sorted[pos] = ei[e] | (rid[e] << 12) | (nf[e] << 22);
}

// one node per block; 2 edge-lanes x 128 dims; fuses buildq (q = bf16(0.1x+aggr))
__global__ __launch_bounds__(256) void k_aggr(
    const int* __restrict__ off, const int* __restrict__ sorted,
    const float* __restrict__ x, const float* __restrict__ rel,
    unsigned short* __restrict__ q)
{
  __shared__ float sAcc[128];
  const int n = blockIdx.x;
  const int t = threadIdx.x;
  const int d = t & 127;
  const int half = t >> 7;
  const int b = off[n], eN = off[n + 1];
  float acc = 0.f;
  for (int i = b + half; i < eN; i += 2) {
    int p = sorted[i];
    float s = x[(p & 4095) * DIM + d] + rel[((p >> 12) & 1023) * DIM + d];
    acc += (p & (1 << 22)) ? -s : s;
  }
  if (half) sAcc[d] = acc;
  __syncthreads();
  if (!half) q[n * DIM + d] = f2bf(0.1f * x[n * DIM + d] + acc + sAcc[d]);
}

// ---------------- prep: E f32 -> bf16 row-major (scale-folded) + transposed (raw) ----
__global__ __launch_bounds__(256) void k_prep(
    const float* __restrict__ ent, const float* __restrict__ scale,
    unsigned short* __restrict__ ebf, unsigned short* __restrict__ etbf)
{
  __shared__ float sT[64 * 133];
  const int t = threadIdx.x;
  const int e0 = blockIdx.x * 64;
#pragma unroll
  for (int i = 0; i < 8; ++i) {
    int idx = i * 256 + t;        // 0..2047
    int e = idx >> 5;             // 0..63
    int c4 = idx & 31;            // float4 chunk
    float4 v = make_float4(0.f, 0.f, 0.f, 0.f);
    float sc = 0.f;
    if (e0 + e < NENT) {
      v = reinterpret_cast<const float4*>(ent)[(e0 + e) * 32 + c4];
      sc = scale[e0 + e];
    }
    *reinterpret_cast<float4*>(&sT[e * 133 + c4 * 4]) = v;  // raw for transpose
    ushort4 bq;  // scale-folded row-major copy (S-phase operand)
    bq.x = f2bf(v.x * sc); bq.y = f2bf(v.y * sc);
    bq.z = f2bf(v.z * sc); bq.w = f2bf(v.w * sc);
    *reinterpret_cast<ushort4*>(&ebf[(e0 + e) * 128 + c4 * 4]) = bq;
  }
  __syncthreads();
  const int lane = t & 63;
  const int w = t >> 6;
  const int dl = lane >> 3;
  const int el = (lane & 7) * 8;
#pragma unroll
  for (int it = 0; it < 4; ++it) {
    int d = it * 32 + w * 8 + dl;
    ushort8 buf;
#pragma unroll
    for (int j = 0; j < 8; ++j) buf[j] = f2bf(sT[(el + j) * 133 + d]);
    *reinterpret_cast<ushort8*>(&etbf[d * NENTP + e0 + el]) = buf;
  }
}

// ---------------- fused relu-"attention" with register-prefetch double buffer ----------
__global__ __launch_bounds__(512, 4) void k_flash(
    const unsigned short* __restrict__ qg,     // [4096][128] bf16
    const unsigned short* __restrict__ ebf,    // [50048][128] bf16, scale-folded
    const unsigned short* __restrict__ etbf,   // [128][50048] bf16, raw
    const float* __restrict__ bias,            // [50000] f32
    float* __restrict__ out)                   // [4096][128] f32 accum
{
  __shared__ __align__(16) unsigned short sE[64 * 136];   // E-tile row-major (scaled)
  __shared__ __align__(16) unsigned short sET[128 * 72];  // E-tile transposed; Q staging
  __shared__ __align__(16) unsigned short sP[128 * 72];   // P tile
  __shared__ float sBias[64];

  const int t = threadIdx.x;
  const int lane = t & 63;
  const int w = t >> 6;
  const int wm = w >> 1;
  const int wn = w & 1;
  const int l15 = lane & 15;
  const int quad = lane >> 4;

  const int m0 = blockIdx.x * 128;
  const int tile_lo = blockIdx.y * CHUNK;
  const int tile_hi = (tile_lo + CHUNK < NTILES) ? (tile_lo + CHUNK) : NTILES;

  // staging index precompute (loop-invariant)
  const int vA0 = t >> 4,          chA0 = t & 15;          // sE chunk 0
  const int vA1 = (512 + t) >> 4,  chA1 = t & 15;          // sE chunk 1
  const int dT0 = t >> 3,          chT0 = t & 7;           // sET chunk 0
  const int dT1 = (512 + t) >> 3,  chT1 = t & 7;           // sET chunk 1

  // ---- stage Q through sET in two 64-row halves; preload A-frags to regs ----
  short8 qf[2][4];
  for (int h = 0; h < 2; ++h) {
#pragma unroll
    for (int i = 0; i < 2; ++i) {
      int idx = i * 512 + t;
      int v = idx >> 4, ch = idx & 15;
      uint4 val = reinterpret_cast<const uint4*>(qg)[(m0 + h * 64 + v) * 16 + ch];
      *reinterpret_cast<uint4*>(&sET[v * 136 + ch * 8]) = val;
    }
    __syncthreads();
    if ((wm >> 1) == h) {
      int lr = (wm & 1) * 32;
#pragma unroll
      for (int tm = 0; tm < 2; ++tm)
#pragma unroll
        for (int kk = 0; kk < 4; ++kk)
          qf[tm][kk] = *reinterpret_cast<const short8*>(
              &sET[(lr + tm * 16 + l15) * 136 + kk * 32 + quad * 8]);
    }
    __syncthreads();
  }

  f32x4 accO[2][4];
#pragma unroll
  for (int tm = 0; tm < 2; ++tm)
#pragma unroll
    for (int td = 0; td < 4; ++td) accO[tm][td] = {0.f, 0.f, 0.f, 0.f};

  // ---- prefetch first tile into registers ----
  uint4 rE0, rE1, rT0, rT1;
  float rB;
  {
    const int vt0 = tile_lo * 64;
    rE0 = *reinterpret_cast<const uint4*>(&ebf[(vt0 + vA0) * 128 + chA0 * 8]);
    rE1 = *reinterpret_cast<const uint4*>(&ebf[(vt0 + vA1) * 128 + chA1 * 8]);
    rT0 = *reinterpret_cast<const uint4*>(&etbf[dT0 * NENTP + vt0 + chT0 * 8]);
    rT1 = *reinterpret_cast<const uint4*>(&etbf[dT1 * NENTP + vt0 + chT1 * 8]);
    rB = (t < 64 && vt0 + t < NENT) ? bias[vt0 + t] : 0.f;
  }

  for (int tile = tile_lo; tile < tile_hi; ++tile) {
    // ---- commit prefetched regs to LDS ----
    *reinterpret_cast<uint4*>(&sE[vA0 * 136 + chA0 * 8]) = rE0;
    *reinterpret_cast<uint4*>(&sE[vA1 * 136 + chA1 * 8]) = rE1;
    *reinterpret_cast<uint4*>(&sET[dT0 * 72 + chT0 * 8]) = rT0;
    *reinterpret_cast<uint4*>(&sET[dT1 * 72 + chT1 * 8]) = rT1;
    if (t < 64) sBias[t] = rB;
    __syncthreads();

    // ---- issue next-tile loads (overlap with S/epilogue/O compute) ----
    if (tile + 1 < tile_hi) {
      const int vt0n = (tile + 1) * 64;
      rE0 = *reinterpret_cast<const uint4*>(&ebf[(vt0n + vA0) * 128 + chA0 * 8]);
      rE1 = *reinterpret_cast<const uint4*>(&ebf[(vt0n + vA1) * 128 + chA1 * 8]);
      rT0 = *reinterpret_cast<const uint4*>(&etbf[dT0 * NENTP + vt0n + chT0 * 8]);
      rT1 = *reinterpret_cast<const uint4*>(&etbf[dT1 * NENTP + vt0n + chT1 * 8]);
      rB = (t < 64 && vt0n + t < NENT) ? bias[vt0n + t] : 0.f;
    }

    // ---- S = Q @ (E*scale)^T : wave computes S[32][32] ----
    f32x4 accS[2][2];
#pragma unroll
    for (int tm = 0; tm < 2; ++tm)
#pragma unroll
      for (int tn = 0; tn < 2; ++tn) accS[tm][tn] = {0.f, 0.f, 0.f, 0.f};
#pragma unroll
    for (int kk = 0; kk < 4; ++kk) {
      short8 bE[2];
#pragma unroll
      for (int tn = 0; tn < 2; ++tn)
        bE[tn] = *reinterpret_cast<const short8*>(
            &sE[(wn * 32 + tn * 16 + l15) * 136 + kk * 32 + quad * 8]);
#pragma unroll
      for (int tm = 0; tm < 2; ++tm)
#pragma unroll
        for (int tn = 0; tn < 2; ++tn)
          accS[tm][tn] = __builtin_amdgcn_mfma_f32_16x16x32_bf16(
              qf[tm][kk], bE[tn], accS[tm][tn], 0, 0, 0);
    }

    // ---- epilogue: P = bf16(relu(S + bias)) ----
#pragma unroll
    for (int tm = 0; tm < 2; ++tm)
#pragma unroll
      for (int tn = 0; tn < 2; ++tn) {
        int col = wn * 32 + tn * 16 + l15;
        float bs = sBias[col];
#pragma unroll
        for (int r = 0; r < 4; ++r) {
          int row = wm * 32 + tm * 16 + quad * 4 + r;
          sP[row * 72 + col] = f2bf(fmaxf(accS[tm][tn][r] + bs, 0.f));
        }
      }
    __syncthreads();

    // ---- O += P @ E : wave computes O[32][64] ----
#pragma unroll
    for (int kk = 0; kk < 2; ++kk) {
      short8 aP[2], bT[4];
#pragma unroll
      for (int tm = 0; tm < 2; ++tm)
        aP[tm] = *reinterpret_cast<const short8*>(
            &sP[(wm * 32 + tm * 16 + l15) * 72 + kk * 32 + quad * 8]);
#pragma unroll
      for (int td = 0; td < 4; ++td)
        bT[td] = *reinterpret_cast<const short8*>(
            &sET[(wn * 64 + td * 16 + l15) * 72 + kk * 32 + quad * 8]);
#pragma unroll
      for (int tm = 0; tm < 2; ++tm)
#pragma unroll
        for (int td = 0; td < 4; ++td)
          accO[tm][td] = __builtin_amdgcn_mfma_f32_16x16x32_bf16(
              aP[tm], bT[td], accO[tm][td], 0, 0, 0);
    }
    __syncthreads();
  }

  // ---- accumulate partial O into f32 output ----
#pragma unroll
  for (int tm = 0; tm < 2; ++tm)
#pragma unroll
    for (int td = 0; td < 4; ++td)
#pragma unroll
      for (int r = 0; r < 4; ++r) {
        int row = m0 + wm * 32 + tm * 16 + quad * 4 + r;
        int col = wn * 64 + td * 16 + l15;
        atomicAdd(&out[row * DIM + col], accO[tm][td][r]);
      }
}

extern "C" void kernel_launch(void* const* d_in, const int* in_sizes, int n_in,
                              void* d_out, int out_size, void* d_ws, size_t ws_size,
                              hipStream_t stream) {
  const float* x     = (const float*)d_in[0];
  const int*   ei    = (const int*)d_in[1];
  const int*   rid   = (const int*)d_in[2];
  const int*   nf    = (const int*)d_in[3];
  const float* rel   = (const float*)d_in[4];
  const float* ent   = (const float*)d_in[5];
  const float* scale = (const float*)d_in[6];
  const float* bias  = (const float*)d_in[7];
  float* out = (float*)d_out;

  // workspace layout (~28.4 MB)
  char* ws = (char*)d_ws;
  int*            cnt    = (int*)(ws + 0);                 // 16 KB
  int*            off    = (int*)(ws + (16u << 10));       // 16.4 KB
  int*            cur    = (int*)(ws + (36u << 10));       // 16 KB
  int*            sorted = (int*)(ws + (64u << 10));       // 1 MB
  unsigned short* qb     = (unsigned short*)(ws + (1344u << 10)); // 1 MB
  unsigned short* ebf    = (unsigned short*)(ws + (2560u << 10)); // 12.81 MB
  unsigned short* etbf   = (unsigned short*)(ws + (2560u << 10) + (size_t)NENTP * DIM * 2);

  hipMemsetAsync(cnt, 0, 4096 * sizeof(int), stream);
  hipMemsetAsync(d_out, 0, (size_t)out_size * sizeof(float), stream);
  k_prep<<<NTILES, 256, 0, stream>>>(ent, scale, ebf, etbf);
  k_hist<<<NEDGES / 256, 256, 0, stream>>>(ei, cnt);
  k_scan<<<1, 1024, 0, stream>>>(cnt, off, cur);
  k_place<<<NEDGES / 256, 256, 0, stream>>>(ei, rid, nf, cur, sorted);
  k_aggr<<<NNODES, 256, 0, stream>>>(off, sorted, x, rel, qb);
  k_flash<<<dim3(NNODES / 128, NSPLIT), 512, 0, stream>>>(qb, ebf, etbf, bias, out);
}

// Round 5
// 282.659 us; speedup vs baseline: 1.2555x; 1.0632x over previous
//
#include <hip/hip_runtime.h>
#include <stdint.h>

typedef __attribute__((ext_vector_type(8))) short short8;
typedef __attribute__((ext_vector_type(8))) unsigned short ushort8;
typedef __attribute__((ext_vector_type(4))) float f32x4;

#define NNODES 4096
#define NEDGES 262144
#define DIM 128
#define NENT 50000
#define NENTP 50048  // padded to 782*64
#define NTILES 782   // ceil(50000/64)
#define NSPLIT 16
#define CHUNK 49     // ceil(782/16)

__device__ __forceinline__ unsigned short f2bf(float f) {
  union { __bf16 b; unsigned short u; } c;
  c.b = (__bf16)f;   // RNE; gfx950 has HW bf16 cvt
  return c.u;
}

// ---------------- scatter pipeline: hist -> scan -> place -> aggregate ----------------
__global__ __launch_bounds__(256) void k_hist(
    const int* __restrict__ ei, int* __restrict__ cnt)
{
  int e = blockIdx.x * 256 + threadIdx.x;
  atomicAdd(&cnt[ei[NEDGES + e]], 1);
}

__global__ __launch_bounds__(1024) void k_scan(
    const int* __restrict__ cnt, int* __restrict__ off, int* __restrict__ cur)
{
  __shared__ int s[1024];
  int t = threadIdx.x;
  int4 v = reinterpret_cast<const int4*>(cnt)[t];
  int lsum = v.x + v.y + v.z + v.w;
  s[t] = lsum; __syncthreads();
  for (int d = 1; d < 1024; d <<= 1) {
    int a = (t >= d) ? s[t - d] : 0;
    __syncthreads();
    s[t] += a;
    __syncthreads();
  }
  int base = s[t] - lsum;  // exclusive prefix
  int4 o; o.x = base; o.y = base + v.x; o.z = o.y + v.y; o.w = o.z + v.z;
  reinterpret_cast<int4*>(off)[t] = o;
  reinterpret_cast<int4*>(cur)[t] = o;
  if (t == 1023) off[4096] = base + lsum;
}

__global__ __launch_bounds__(256) void k_place(
    const int* __restrict__ ei, const int* __restrict__ rid,
    const int* __restrict__ nf, int* __restrict__ cur, int* __restrict__ sorted)
{
  int e = blockIdx.x * 256 + threadIdx.x;
  int dst = ei[NEDGES + e];
  int pos = atomicAdd(&cur[dst], 1);
  sorted[pos] = ei[e] | (rid[e] << 12) | (nf[e] << 22);
}

// one node per block; 8 edge-slots x 32 float4-lanes (8 edges in flight, 16B gathers)
// fuses buildq: q = bf16(0.1*x + aggr)
__global__ __launch_bounds__(256) void k_aggr(
    const int* __restrict__ off, const int* __restrict__ sorted,
    const float* __restrict__ x, const float* __restrict__ rel,
    unsigned short* __restrict__ q)
{
  __shared__ float sAcc[8 * 132];   // slot-major, pad 132 -> conflict-free
  const int n = blockIdx.x;
  const int t = threadIdx.x;
  const int slot = t >> 5;          // 0..7
  const int c = t & 31;             // float4 chunk (dims 4c..4c+3)
  const int b = off[n], eN = off[n + 1];
  float4 acc = make_float4(0.f, 0.f, 0.f, 0.f);
  for (int i = b + slot; i < eN; i += 8) {
    int p = sorted[i];
    float4 xv = reinterpret_cast<const float4*>(x)[(p & 4095) * 32 + c];
    float4 rv = reinterpret_cast<const float4*>(rel)[((p >> 12) & 1023) * 32 + c];
    float sgn = (p & (1 << 22)) ? -1.f : 1.f;
    acc.x += sgn * (xv.x + rv.x);
    acc.y += sgn * (xv.y + rv.y);
    acc.z += sgn * (xv.z + rv.z);
    acc.w += sgn * (xv.w + rv.w);
  }
  *reinterpret_cast<float4*>(&sAcc[slot * 132 + c * 4]) = acc;
  __syncthreads();
  if (t < 128) {
    float s = 0.f;
#pragma unroll
    for (int k = 0; k < 8; ++k) s += sAcc[k * 132 + t];
    q[n * DIM + t] = f2bf(0.1f * x[n * DIM + t] + s);
  }
}

// ---------------- prep: E f32 -> bf16 row-major (scale-folded) + transposed (raw) ----
__global__ __launch_bounds__(256) void k_prep(
    const float* __restrict__ ent, const float* __restrict__ scale,
    unsigned short* __restrict__ ebf, unsigned short* __restrict__ etbf)
{
  __shared__ float sT[64 * 133];
  const int t = threadIdx.x;
  const int e0 = blockIdx.x * 64;
#pragma unroll
  for (int i = 0; i < 8; ++i) {
    int idx = i * 256 + t;        // 0..2047
    int e = idx >> 5;             // 0..63
    int c4 = idx & 31;            // float4 chunk
    float4 v = make_float4(0.f, 0.f, 0.f, 0.f);
    float sc = 0.f;
    if (e0 + e < NENT) {
      v = reinterpret_cast<const float4*>(ent)[(e0 + e) * 32 + c4];
      sc = scale[e0 + e];
    }
    *reinterpret_cast<float4*>(&sT[e * 133 + c4 * 4]) = v;  // raw for transpose
    ushort4 bq;  // scale-folded row-major copy (S-phase operand)
    bq.x = f2bf(v.x * sc); bq.y = f2bf(v.y * sc);
    bq.z = f2bf(v.z * sc); bq.w = f2bf(v.w * sc);
    *reinterpret_cast<ushort4*>(&ebf[(e0 + e) * 128 + c4 * 4]) = bq;
  }
  __syncthreads();
  const int lane = t & 63;
  const int w = t >> 6;
  const int dl = lane >> 3;
  const int el = (lane & 7) * 8;
#pragma unroll
  for (int it = 0; it < 4; ++it) {
    int d = it * 32 + w * 8 + dl;
    ushort8 buf;
#pragma unroll
    for (int j = 0; j < 8; ++j) buf[j] = f2bf(sT[(el + j) * 133 + d]);
    *reinterpret_cast<ushort8*>(&etbf[d * NENTP + e0 + el]) = buf;
  }
}

// ---------------- fused relu-"attention" with register-prefetch double buffer ----------
__global__ __launch_bounds__(512, 4) void k_flash(
    const unsigned short* __restrict__ qg,     // [4096][128] bf16
    const unsigned short* __restrict__ ebf,    // [50048][128] bf16, scale-folded
    const unsigned short* __restrict__ etbf,   // [128][50048] bf16, raw
    const float* __restrict__ bias,            // [50000] f32
    float* __restrict__ out)                   // [4096][128] f32 accum
{
  __shared__ __align__(16) unsigned short sE[64 * 136];   // E-tile row-major (scaled)
  __shared__ __align__(16) unsigned short sET[128 * 72];  // E-tile transposed; Q staging
  __shared__ __align__(16) unsigned short sP[128 * 72];   // P tile
  __shared__ float sBias[64];

  const int t = threadIdx.x;
  const int lane = t & 63;
  const int w = t >> 6;
  const int wm = w >> 1;
  const int wn = w & 1;
  const int l15 = lane & 15;
  const int quad = lane >> 4;

  const int m0 = blockIdx.x * 128;
  const int tile_lo = blockIdx.y * CHUNK;
  const int tile_hi = (tile_lo + CHUNK < NTILES) ? (tile_lo + CHUNK) : NTILES;

  // staging index precompute (loop-invariant)
  const int vA0 = t >> 4,          chA0 = t & 15;          // sE chunk 0
  const int vA1 = (512 + t) >> 4,  chA1 = t & 15;          // sE chunk 1
  const int dT0 = t >> 3,          chT0 = t & 7;           // sET chunk 0
  const int dT1 = (512 + t) >> 3,  chT1 = t & 7;           // sET chunk 1

  // ---- stage Q through sET in two 64-row halves; preload A-frags to regs ----
  short8 qf[2][4];
  for (int h = 0; h < 2; ++h) {
#pragma unroll
    for (int i = 0; i < 2; ++i) {
      int idx = i * 512 + t;
      int v = idx >> 4, ch = idx & 15;
      uint4 val = reinterpret_cast<const uint4*>(qg)[(m0 + h * 64 + v) * 16 + ch];
      *reinterpret_cast<uint4*>(&sET[v * 136 + ch * 8]) = val;
    }
    __syncthreads();
    if ((wm >> 1) == h) {
      int lr = (wm & 1) * 32;
#pragma unroll
      for (int tm = 0; tm < 2; ++tm)
#pragma unroll
        for (int kk = 0; kk < 4; ++kk)
          qf[tm][kk] = *reinterpret_cast<const short8*>(
              &sET[(lr + tm * 16 + l15) * 136 + kk * 32 + quad * 8]);
    }
    __syncthreads();
  }

  f32x4 accO[2][4];
#pragma unroll
  for (int tm = 0; tm < 2; ++tm)
#pragma unroll
    for (int td = 0; td < 4; ++td) accO[tm][td] = {0.f, 0.f, 0.f, 0.f};

  // ---- prefetch first tile into registers ----
  uint4 rE0, rE1, rT0, rT1;
  float rB;
  {
    const int vt0 = tile_lo * 64;
    rE0 = *reinterpret_cast<const uint4*>(&ebf[(vt0 + vA0) * 128 + chA0 * 8]);
    rE1 = *reinterpret_cast<const uint4*>(&ebf[(vt0 + vA1) * 128 + chA1 * 8]);
    rT0 = *reinterpret_cast<const uint4*>(&etbf[dT0 * NENTP + vt0 + chT0 * 8]);
    rT1 = *reinterpret_cast<const uint4*>(&etbf[dT1 * NENTP + vt0 + chT1 * 8]);
    rB = (t < 64 && vt0 + t < NENT) ? bias[vt0 + t] : 0.f;
  }

  for (int tile = tile_lo; tile < tile_hi; ++tile) {
    // ---- commit prefetched regs to LDS ----
    *reinterpret_cast<uint4*>(&sE[vA0 * 136 + chA0 * 8]) = rE0;
    *reinterpret_cast<uint4*>(&sE[vA1 * 136 + chA1 * 8]) = rE1;
    *reinterpret_cast<uint4*>(&sET[dT0 * 72 + chT0 * 8]) = rT0;
    *reinterpret_cast<uint4*>(&sET[dT1 * 72 + chT1 * 8]) = rT1;
    if (t < 64) sBias[t] = rB;
    __syncthreads();

    // ---- issue next-tile loads (overlap with S/epilogue/O compute) ----
    if (tile + 1 < tile_hi) {
      const int vt0n = (tile + 1) * 64;
      rE0 = *reinterpret_cast<const uint4*>(&ebf[(vt0n + vA0) * 128 + chA0 * 8]);
      rE1 = *reinterpret_cast<const uint4*>(&ebf[(vt0n + vA1) * 128 + chA1 * 8]);
      rT0 = *reinterpret_cast<const uint4*>(&etbf[dT0 * NENTP + vt0n + chT0 * 8]);
      rT1 = *reinterpret_cast<const uint4*>(&etbf[dT1 * NENTP + vt0n + chT1 * 8]);
      rB = (t < 64 && vt0n + t < NENT) ? bias[vt0n + t] : 0.f;
    }

    // ---- S = Q @ (E*scale)^T : wave computes S[32][32] ----
    f32x4 accS[2][2];
#pragma unroll
    for (int tm = 0; tm < 2; ++tm)
#pragma unroll
      for (int tn = 0; tn < 2; ++tn) accS[tm][tn] = {0.f, 0.f, 0.f, 0.f};
#pragma unroll
    for (int kk = 0; kk < 4; ++kk) {
      short8 bE[2];
#pragma unroll
      for (int tn = 0; tn < 2; ++tn)
        bE[tn] = *reinterpret_cast<const short8*>(
            &sE[(wn * 32 + tn * 16 + l15) * 136 + kk * 32 + quad * 8]);
#pragma unroll
      for (int tm = 0; tm < 2; ++tm)
#pragma unroll
        for (int tn = 0; tn < 2; ++tn)
          accS[tm][tn] = __builtin_amdgcn_mfma_f32_16x16x32_bf16(
              qf[tm][kk], bE[tn], accS[tm][tn], 0, 0, 0);
    }

    // ---- epilogue: P = bf16(relu(S + bias)) ----
#pragma unroll
    for (int tm = 0; tm < 2; ++tm)
#pragma unroll
      for (int tn = 0; tn < 2; ++tn) {
        int col = wn * 32 + tn * 16 + l15;
        float bs = sBias[col];
#pragma unroll
        for (int r = 0; r < 4; ++r) {
          int row = wm * 32 + tm * 16 + quad * 4 + r;
          sP[row * 72 + col] = f2bf(fmaxf(accS[tm][tn][r] + bs, 0.f));
        }
      }
    __syncthreads();

    // ---- O += P @ E : wave computes O[32][64] ----
#pragma unroll
    for (int kk = 0; kk < 2; ++kk) {
      short8 aP[2], bT[4];
#pragma unroll
      for (int tm = 0; tm < 2; ++tm)
        aP[tm] = *reinterpret_cast<const short8*>(
            &sP[(wm * 32 + tm * 16 + l15) * 72 + kk * 32 + quad * 8]);
#pragma unroll
      for (int td = 0; td < 4; ++td)
        bT[td] = *reinterpret_cast<const short8*>(
            &sET[(wn * 64 + td * 16 + l15) * 72 + kk * 32 + quad * 8]);
#pragma unroll
      for (int tm = 0; tm < 2; ++tm)
#pragma unroll
        for (int td = 0; td < 4; ++td)
          accO[tm][td] = __builtin_amdgcn_mfma_f32_16x16x32_bf16(
              aP[tm], bT[td], accO[tm][td], 0, 0, 0);
    }
    __syncthreads();
  }

  // ---- accumulate partial O into f32 output ----
#pragma unroll
  for (int tm = 0; tm < 2; ++tm)
#pragma unroll
    for (int td = 0; td < 4; ++td)
#pragma unroll
      for (int r = 0; r < 4; ++r) {
        int row = m0 + wm * 32 + tm * 16 + quad * 4 + r;
        int col = wn * 64 + td * 16 + l15;
        atomicAdd(&out[row * DIM + col], accO[tm][td][r]);
      }
}

extern "C" void kernel_launch(void* const* d_in, const int* in_sizes, int n_in,
                              void* d_out, int out_size, void* d_ws, size_t ws_size,
                              hipStream_t stream) {
  const float* x     = (const float*)d_in[0];
  const int*   ei    = (const int*)d_in[1];
  const int*   rid   = (const int*)d_in[2];
  const int*   nf    = (const int*)d_in[3];
  const float* rel   = (const float*)d_in[4];
  const float* ent   = (const float*)d_in[5];
  const float* scale = (const float*)d_in[6];
  const float* bias  = (const float*)d_in[7];
  float* out = (float*)d_out;

  // workspace layout (~28.4 MB)
  char* ws = (char*)d_ws;
  int*            cnt    = (int*)(ws + 0);                 // 16 KB
  int*            off    = (int*)(ws + (16u << 10));       // 16.4 KB
  int*            cur    = (int*)(ws + (36u << 10));       // 16 KB
  int*            sorted = (int*)(ws + (64u << 10));       // 1 MB
  unsigned short* qb     = (unsigned short*)(ws + (1344u << 10)); // 1 MB
  unsigned short* ebf    = (unsigned short*)(ws + (2560u << 10)); // 12.81 MB
  unsigned short* etbf   = (unsigned short*)(ws + (2560u << 10) + (size_t)NENTP * DIM * 2);

  hipMemsetAsync(cnt, 0, 4096 * sizeof(int), stream);
  hipMemsetAsync(d_out, 0, (size_t)out_size * sizeof(float), stream);
  k_prep<<<NTILES, 256, 0, stream>>>(ent, scale, ebf, etbf);
  k_hist<<<NEDGES / 256, 256, 0, stream>>>(ei, cnt);
  k_scan<<<1, 1024, 0, stream>>>(cnt, off, cur);
  k_place<<<NEDGES / 256, 256, 0, stream>>>(ei, rid, nf, cur, sorted);
  k_aggr<<<NNODES, 256, 0, stream>>>(off, sorted, x, rel, qb);
  k_flash<<<dim3(NNODES / 128, NSPLIT), 512, 0, stream>>>(qb, ebf, etbf, bias, out);
}